// Round 9
// baseline (157.287 us; speedup 1.0000x reference)
//
#include <hip/hip_runtime.h>

#define NB 8192
#define NL 64
#define NH 128

typedef __bf16 bf16x8 __attribute__((ext_vector_type(8)));
typedef float f32x4 __attribute__((ext_vector_type(4)));
typedef float f32x2 __attribute__((ext_vector_type(2)));
typedef unsigned uint4v __attribute__((ext_vector_type(4)));
typedef unsigned short ushort8 __attribute__((ext_vector_type(8)));

// phys->logical permutation for the h buffer (GEMM1 writeback pair-packing):
// phys p = w*32 + 2e (+1) holds logical w*32 + e (+16)
__device__ __host__ __forceinline__ int p2l(int p) {
  return (p & ~31) + ((p & 1) << 4) + ((p & 31) >> 1);
}
// phys->logical permutation for the x=concat(x1,x2) buffer (x1x2 pair-packing):
// phys even p -> x1 col p/2 ; phys odd p -> x2 col p/2 (logical 64+p/2)
__device__ __host__ __forceinline__ int pi2(int p) {
  return (p & 1) ? 64 + (p >> 1) : (p >> 1);
}

__device__ __forceinline__ unsigned pk2(float lo, float hi) {
  union { __bf16 b[2]; unsigned u; } t;
  t.b[0] = (__bf16)lo; t.b[1] = (__bf16)hi;
  return t.u;
}

// ---------------------------------------------------------------------------
// Repack weights (f32 -> bf16 MFMA fragments; A/B share the lane map so this
// is unchanged from R8) + permuted f32 gamma/beta.
// wp1: [layer3][ntile8][kstep4][lane64][reg8]; value = W1[l][srck][n]
//      srck = k (layer 0) | pi2(k) (layers 1,2)   [x-buffer phys layout]
// wp2: [layer3][ntile4][kstep4][lane64][reg8]; value = W2[l][p2l(k)][n]
// gbt: f32 [layer3][2][4(q)][36]; gbt[l][g][q][k] = param[l][p2l(q*32+k)]
// ---------------------------------------------------------------------------
__global__ __launch_bounds__(256) void repack_w(const float* __restrict__ W1,
                                                const float* __restrict__ W2,
                                                const float* __restrict__ gamma,
                                                const float* __restrict__ beta,
                                                unsigned short* __restrict__ wp1,
                                                unsigned short* __restrict__ wp2,
                                                float* __restrict__ gbt) {
  int t = blockIdx.x * 256 + threadIdx.x;
  int lane = t & 63, g = t >> 6;
  if (g < 96) {                                   // W1: 3*8*4 groups
    int layer = g >> 5, rem = g & 31, nt = rem >> 2, ks = rem & 3;
    int n = nt * 16 + (lane & 15);
    int kb = ks * 32 + (lane >> 4) * 8;
    ushort8 v;
#pragma unroll
    for (int r = 0; r < 8; ++r) {
      int k = kb + r;
      int srck = (layer == 0) ? k : pi2(k);
      union { __bf16 b; unsigned short u; } c;
      c.b = (__bf16)W1[(layer * 128 + srck) * 128 + n];
      v[r] = c.u;
    }
    *reinterpret_cast<ushort8*>(wp1 + ((size_t)g * 64 + lane) * 8) = v;
  } else if (g < 144) {                           // W2: 3*4*4 groups, k by p2l
    int g2 = g - 96;
    int layer = g2 >> 4, rem = g2 & 15, nt = rem >> 2, ks = rem & 3;
    int n = nt * 16 + (lane & 15);
    int kb = ks * 32 + (lane >> 4) * 8;
    ushort8 v;
#pragma unroll
    for (int r = 0; r < 8; ++r) {
      union { __bf16 b; unsigned short u; } c;
      c.b = (__bf16)W2[(layer * 128 + p2l(kb + r)) * 64 + n];
      v[r] = c.u;
    }
    *reinterpret_cast<ushort8*>(wp2 + ((size_t)g2 * 64 + lane) * 8) = v;
  } else if (g < 150) {                           // gamma/beta f32, padded
    int g2 = g - 144;                             // 0..5
    int layer = g2 >> 1, param = g2 & 1;
    const float* src = (param == 0 ? gamma : beta) + layer * 128;
    float* dst = gbt + layer * 288 + param * 144;
    int p0 = lane * 2;
#pragma unroll
    for (int u = 0; u < 2; ++u) {
      int p = p0 + u;
      dst[(p >> 5) * 36 + (p & 31)] = src[p2l(p)];
    }
  }
}

// ---------------------------------------------------------------------------
// Fused depth-3 MLP stack, one workgroup (4 waves) per batch row b.
// TRANSPOSED GEMMs: D = W^T (A operand) x activation (B operand), so each
// lane's 4 acc values are 4 consecutive output dwords in ONE row ->
// ds_write_b128 epilogues (was 16x ds_write_b32). Two LDS buffers
// (xA = x, xB = h/xn), bf16 [64][128], swizzle byte ^= ((row&15)<<4),
// 3 barriers/layer. No W-prefetch, no min-waves bound (R4/R6: spills).
// ---------------------------------------------------------------------------
__global__ __launch_bounds__(256) void fused_mlp(
    const float* __restrict__ hidden,
    const float* __restrict__ b1,
    const float* __restrict__ b2,
    const unsigned short* __restrict__ wp1u,
    const unsigned short* __restrict__ wp2u,
    const float* __restrict__ gbt,
    float* __restrict__ out) {
  __shared__ __align__(16) unsigned short xAu[NL * NH];    // 16384 B (x)
  __shared__ __align__(16) unsigned short xBu[NL * NH];    // 16384 B (h/xn)
  __shared__ __align__(16) float gbuf[864];                // 3456 B

  const int tid = threadIdx.x;
  const int wave = tid >> 6, lane = tid & 63;
  const int ci = lane & 15, lg = lane >> 4;
  char* xA = reinterpret_cast<char*>(xAu);
  char* xB = reinterpret_cast<char*>(xBu);

  // B-fragment read pieces: row = mt*16+ci, k-bytes = ks*64+lg*16
  const int abase = ci * 256;
  const int axor = ci << 4;
  // b128 writeback base: row = mt*16+ci, dword cols wave*16+lg*4..+3
  const int wbase = ci * 256 + ((wave * 64 + lg * 16) ^ axor);

  // stage gamma/beta (f32, padded layout) into LDS
  if (tid < 96) {
#pragma unroll
    for (int u = 0; u < 9; ++u) gbuf[tid * 9 + u] = gbt[tid * 9 + u];
  }

  // ---- stage 0: load hidden[b] (f32) -> xA (bf16, swizzled, identity) ----
  const float* src = hidden + (size_t)blockIdx.x * (NL * NH);
#pragma unroll
  for (int i = 0; i < 4; ++i) {
    int f = i * 256 + tid;          // 8-elem chunk id, 0..1023
    int row = f >> 4;
    int cb = (f & 15) * 16;         // byte column
    const float4* p = reinterpret_cast<const float4*>(src + f * 8);
    float4 a = p[0], bq = p[1];
    bf16x8 v;
    v[0] = (__bf16)a.x;  v[1] = (__bf16)a.y;  v[2] = (__bf16)a.z;  v[3] = (__bf16)a.w;
    v[4] = (__bf16)bq.x; v[5] = (__bf16)bq.y; v[6] = (__bf16)bq.z; v[7] = (__bf16)bq.w;
    *reinterpret_cast<bf16x8*>(xA + row * 256 + (cb ^ ((row & 15) << 4))) = v;
  }
  __syncthreads();

  for (int layer = 0; layer < 3; ++layer) {
    // ========== GEMM1 (transposed): h^T = W1^T(A) x x(B), bias in C-init ====
    const unsigned short* wl1 = wp1u + (size_t)layer * 16384;
    bf16x8 w1f[2][4];
#pragma unroll
    for (int nt2 = 0; nt2 < 2; ++nt2)
#pragma unroll
      for (int ks = 0; ks < 4; ++ks)
        w1f[nt2][ks] = *reinterpret_cast<const bf16x8*>(
            wl1 + (((wave * 2 + nt2) * 4 + ks) * 64 + lane) * 8);
    f32x4 bA = *reinterpret_cast<const f32x4*>(b1 + layer * 128 + wave * 32 + lg * 4);
    f32x4 bB = *reinterpret_cast<const f32x4*>(b1 + layer * 128 + wave * 32 + 16 + lg * 4);
    f32x4 acc[4][2];
#pragma unroll
    for (int mt = 0; mt < 4; ++mt) { acc[mt][0] = bA; acc[mt][1] = bB; }
#pragma unroll
    for (int ks = 0; ks < 4; ++ks) {
      int cbx = ((ks * 64 + lg * 16) ^ axor) + abase;
#pragma unroll
      for (int mt = 0; mt < 4; ++mt) {
        bf16x8 xf = *reinterpret_cast<const bf16x8*>(xA + mt * 4096 + cbx);
        acc[mt][0] = __builtin_amdgcn_mfma_f32_16x16x32_bf16(w1f[0][ks], xf, acc[mt][0], 0, 0, 0);
        acc[mt][1] = __builtin_amdgcn_mfma_f32_16x16x32_bf16(w1f[1][ks], xf, acc[mt][1], 0, 0, 0);
      }
    }
    // writeback h -> xB: per mt one b128 (4 pair-packed dwords, one row)
#pragma unroll
    for (int mt = 0; mt < 4; ++mt) {
      uint4v w;
#pragma unroll
      for (int r = 0; r < 4; ++r) w[r] = pk2(acc[mt][0][r], acc[mt][1][r]);
      *reinterpret_cast<uint4v*>(xB + mt * 4096 + wbase) = w;
    }
    __syncthreads();  // β1: h visible to LN

    // ========== LayerNorm + ReLU on xB in place: 4 threads per row ==========
    {
      const int row = wave * 16 + (lane >> 2);
      const int q = lane & 3;
      const int rb = row * 256, rx = (lane >> 2) << 4;
      bf16x8 h0 = *reinterpret_cast<const bf16x8*>(xB + rb + ((q * 64 + 0) ^ rx));
      bf16x8 h1 = *reinterpret_cast<const bf16x8*>(xB + rb + ((q * 64 + 16) ^ rx));
      bf16x8 h2 = *reinterpret_cast<const bf16x8*>(xB + rb + ((q * 64 + 32) ^ rx));
      bf16x8 h3 = *reinterpret_cast<const bf16x8*>(xB + rb + ((q * 64 + 48) ^ rx));
      f32x2 f[16];
#pragma unroll
      for (int cch = 0; cch < 4; ++cch) {
        bf16x8 hv = (cch == 0) ? h0 : (cch == 1) ? h1 : (cch == 2) ? h2 : h3;
#pragma unroll
        for (int j2 = 0; j2 < 4; ++j2)
          f[cch * 4 + j2] = f32x2{(float)hv[j2 * 2], (float)hv[j2 * 2 + 1]};
      }
      f32x2 s2 = {0.f, 0.f}, q2 = {0.f, 0.f};
#pragma unroll
      for (int i = 0; i < 16; ++i) { s2 += f[i]; q2 += f[i] * f[i]; }
      float s = s2.x + s2.y, sq = q2.x + q2.y;
      s += __shfl_xor(s, 1);  sq += __shfl_xor(sq, 1);
      s += __shfl_xor(s, 2);  sq += __shfl_xor(sq, 2);
      float mu = s * (1.f / 128.f);
      float var = sq * (1.f / 128.f) - mu * mu;
      float rs = rsqrtf(var + 1e-5f);
      const f32x2* gl = reinterpret_cast<const f32x2*>(gbuf + layer * 288 + q * 36);
      const f32x2* bl = reinterpret_cast<const f32x2*>(gbuf + layer * 288 + 144 + q * 36);
#pragma unroll
      for (int cch = 0; cch < 4; ++cch) {
        union { unsigned u[4]; bf16x8 v; } yy;
#pragma unroll
        for (int j2 = 0; j2 < 4; ++j2) {
          int i = cch * 4 + j2;
          f32x2 a2 = gl[i] * rs;
          f32x2 c2 = bl[i] - a2 * mu;
          f32x2 y2 = f[i] * a2 + c2;
          yy.u[j2] = pk2(fmaxf(y2.x, 0.f), fmaxf(y2.y, 0.f));
        }
        *reinterpret_cast<bf16x8*>(xB + rb + ((q * 64 + cch * 16) ^ rx)) = yy.v;
      }
    }
    __syncthreads();  // β2: normalized x visible

    // ========== GEMM2 (transposed): x1^T = W2^T(A) x xn(B), bias in C-init ==
    const unsigned short* wl2 = wp2u + (size_t)layer * 8192;
    bf16x8 w2f[4];
#pragma unroll
    for (int ks = 0; ks < 4; ++ks)
      w2f[ks] = *reinterpret_cast<const bf16x8*>(
          wl2 + ((wave * 4 + ks) * 64 + lane) * 8);
    f32x4 b2v = *reinterpret_cast<const f32x4*>(b2 + layer * 64 + wave * 16 + lg * 4);
    f32x4 acc2[4];
#pragma unroll
    for (int mt = 0; mt < 4; ++mt) acc2[mt] = b2v;
#pragma unroll
    for (int ks = 0; ks < 4; ++ks) {
      int cbx = ((ks * 64 + lg * 16) ^ axor) + abase;
#pragma unroll
      for (int mt = 0; mt < 4; ++mt) {
        bf16x8 xf = *reinterpret_cast<const bf16x8*>(xB + mt * 4096 + cbx);
        acc2[mt] = __builtin_amdgcn_mfma_f32_16x16x32_bf16(w2f[ks], xf, acc2[mt], 0, 0, 0);
      }
    }

    // max-pool over L: max over mt (in-reg) then over ci lanes (4 shfl steps)
    f32x4 mm;
#pragma unroll
    for (int r = 0; r < 4; ++r)
      mm[r] = fmaxf(fmaxf(acc2[0][r], acc2[1][r]), fmaxf(acc2[2][r], acc2[3][r]));
#pragma unroll
    for (int o = 1; o < 16; o <<= 1)
#pragma unroll
      for (int r = 0; r < 4; ++r) mm[r] = fmaxf(mm[r], __shfl_xor(mm[r], o));

    if (layer < 2) {
      // pack (x1^T[n][L], x2[n]) -> xA: per mt one b128 (4 dwords, one row)
      // (xA's readers all finished before β1; no extra barrier needed)
#pragma unroll
      for (int mt = 0; mt < 4; ++mt) {
        uint4v w;
#pragma unroll
        for (int r = 0; r < 4; ++r) w[r] = pk2(acc2[mt][r], mm[r]);
        *reinterpret_cast<uint4v*>(xA + mt * 4096 + wbase) = w;
      }
      __syncthreads();  // β3: new x visible for next layer
    } else {
      // final output (f32): out[b] = [x2_3, x2_3]; mm[r] holds n=w*16+lg*4+r
      if (ci == 0) {
        float* o = out + (size_t)blockIdx.x * 128 + wave * 16 + lg * 4;
        *reinterpret_cast<f32x4*>(o) = mm;
        *reinterpret_cast<f32x4*>(o + 64) = mm;
      }
    }
  }
}

extern "C" void kernel_launch(void* const* d_in, const int* in_sizes, int n_in,
                              void* d_out, int out_size, void* d_ws, size_t ws_size,
                              hipStream_t stream) {
  const float* hidden = (const float*)d_in[0];
  const float* W1 = (const float*)d_in[1];
  const float* b1 = (const float*)d_in[2];
  const float* gamma = (const float*)d_in[3];
  const float* beta = (const float*)d_in[4];
  const float* W2 = (const float*)d_in[5];
  const float* b2 = (const float*)d_in[6];
  (void)in_sizes; (void)n_in; (void)out_size; (void)ws_size;

  unsigned short* wp1 = (unsigned short*)d_ws;          // 49152 ushorts
  unsigned short* wp2 = wp1 + 3 * 8 * 4 * 64 * 8;       // 24576 ushorts
  float* gbt = (float*)(wp2 + 3 * 4 * 4 * 64 * 8);      // 864 f32 (padded)
  float* out = (float*)d_out;

  repack_w<<<38, 256, 0, stream>>>(W1, W2, gamma, beta, wp1, wp2, gbt);
  fused_mlp<<<NB, 256, 0, stream>>>(hidden, b1, b2, wp1, wp2, gbt, out);
}